// Round 3
// baseline (324.983 us; speedup 1.0000x reference)
//
#include <hip/hip_runtime.h>
#include <hip/hip_fp16.h>

// Self-attention B=8 S=2048 D=512, fp32-vs-bf16 input auto-detect.
// R11 = R10 resubmit (container infra died twice before verification;
// source re-audited: uniform barriers, vmcnt ledger checked for BN=256/128,
// overwrite-after-lgkm0+barrier safe, LDS 128/96 KiB, nt even everywhere).
// R10: GEMM restructured to the 8-phase 256-tile template (T2+T3+T4+T5):
// BM=256, BK=64, 512 thr = 8 waves (2Mx4N), mfma_f32_16x16x32_f16 (16-row
// frags -> XOR(row&7) swizzle is 2-way conflict-free), 4 phases per K-tile
// {ds_read quad | raw s_barrier | setprio(1) 16xMFMA setprio(0) | barrier},
// stage burst at tile boundary after lgkmcnt(0)+barrier (overwrite-safe),
// counted vmcnt(8)/(6) -- never 0 in steady state; loads span 4 phases.
// BN templated: 256 (scores/proj), 128 (PV -> grid=256 blocks, 1/CU).
// R9 (2-phase dbuf + syncthreads) regressed 294->304: drain-at-barrier.

typedef unsigned short u16;
typedef unsigned int u32;
typedef __attribute__((ext_vector_type(8))) _Float16 f16x8;
typedef __attribute__((ext_vector_type(4))) float f32x4;

#define S_LEN 2048
#define D_DIM 512
#define B_N 8

__device__ __forceinline__ u16 f2bf(float f) {
    u32 u = __float_as_uint(f);
    u32 r = u + 0x7FFFu + ((u >> 16) & 1u);   // RNE
    return (u16)(r >> 16);
}
__device__ __forceinline__ float bf2f(u16 h) {
    return __uint_as_float((u32)h << 16);
}
__device__ __forceinline__ u16 f2h(float f) {
    _Float16 h = (_Float16)f;                 // RNE
    return *(u16*)&h;
}
__device__ __forceinline__ void gl16(const u16* g, u16* l) {
    __builtin_amdgcn_global_load_lds(
        (const __attribute__((address_space(1))) void*)g,
        (__attribute__((address_space(3))) void*)l, 16, 0, 0);
}
__device__ __forceinline__ f32x4 mfma16(f16x8 a, f16x8 b, f32x4 c) {
    return __builtin_amdgcn_mfma_f32_16x16x32_f16(a, b, c, 0, 0, 0);
}

// ---- dtype detector ----
__global__ void detect_k(const u16* __restrict__ x, int* __restrict__ flag)
{
    int t = threadIdx.x;
    u16 u = x[2 * t];
    int e = (u >> 7) & 0xFF;
    int sane = (e == 0) || (e >= 110 && e <= 140);
    unsigned long long b = __ballot(sane);
    if (t == 0) *flag = (__popcll(b) >= 32) ? 1 : 0;
}

// ---- convert x to fp16 ----
__global__ __launch_bounds__(256) void cvt_x(
    const void* __restrict__ X, u16* __restrict__ xf,
    const int* __restrict__ flagp)
{
    const size_t i4 = ((size_t)blockIdx.x * 256 + threadIdx.x) * 4;
    float f[4];
    if (*flagp) {
        ushort4 u = *(const ushort4*)((const u16*)X + i4);
        f[0] = bf2f(u.x); f[1] = bf2f(u.y); f[2] = bf2f(u.z); f[3] = bf2f(u.w);
    } else {
        float4 ff = *(const float4*)((const float*)X + i4);
        f[0] = ff.x; f[1] = ff.y; f[2] = ff.z; f[3] = ff.w;
    }
    ushort4 h;
    h.x = f2h(f[0]); h.y = f2h(f[1]); h.z = f2h(f[2]); h.w = f2h(f[3]);
    *(ushort4*)(xf + i4) = h;
}

// ---- pack W^T concat (q|k|v) fp16: WT[n 0..1535][k 0..511] ----
__global__ __launch_bounds__(256) void pack_w(
    const void* __restrict__ Wq, const void* __restrict__ Wk, const void* __restrict__ Wv,
    u16* __restrict__ WT, const int* __restrict__ flagp)
{
    const int k = blockIdx.x;
    const int n = blockIdx.y * 256 + threadIdx.x;
    const void* W = n < 512 ? Wq : n < 1024 ? Wk : Wv;
    const int nc = n & 511;
    float f = *flagp ? bf2f(((const u16*)W)[(size_t)k * 512 + nc])
                     : ((const float*)W)[(size_t)k * 512 + nc];
    WT[(size_t)n * 512 + k] = f2h(f);
}

__global__ void pack_bias(
    const void* __restrict__ bq, const void* __restrict__ bk, const void* __restrict__ bv,
    float* __restrict__ bcat, const int* __restrict__ flagp)
{
    const int t = blockIdx.x * 256 + threadIdx.x;
    const void* b = t < 512 ? bq : t < 1024 ? bk : bv;
    const int i = t & 511;
    bcat[t] = *flagp ? bf2f(((const u16*)b)[i]) : ((const float*)b)[i];
}

// ---- 8-phase fp16 BT-GEMM: C[M,N] = A[M,K] * B[N,K]^T ----
// BM=256 x BN (256 or 128), BK=64, 512 threads = 8 waves (2M x 4N).
// Per-wave C: 128 x (BN/4). LDS slot s of row r holds global chunk s^(r&7).
// EPI 0: fp32 C (scores). EPI 1: flag-dtyped C (out). EPI 2: proj q|k|vT +bias.
template <int EPI, int BN>
__global__ __launch_bounds__(512, 2) void gemm8(
    const u16* __restrict__ A_, const u16* __restrict__ B_,
    void* __restrict__ Cp, const float* __restrict__ biasf,
    u16* __restrict__ Oq, u16* __restrict__ Ok, u16* __restrict__ OvT,
    const int* __restrict__ flagp,
    int K, int lda, int ldb, int ldc, long sA, long sB, long sC, long cbase)
{
    constexpr int NJ = BN / 64;          // N-frags per wave (4 or 2)
    constexpr int NB = BN / 64;          // B staging passes (64 rows each)

    const int tid = threadIdx.x;
    const int lane = tid & 63;
    const int wid = tid >> 6;            // 0..7
    const int wm = wid >> 2;             // 0..1  (M half: 128 rows)
    const int wn = wid & 3;              // 0..3  (N quarter: BN/4 cols)
    const int l15 = lane & 15, lq = lane >> 4;
    const int m0 = blockIdx.y * 256, n0 = blockIdx.x * BN;
    const int colB = wn * (BN / 4);

    const u16* A = A_ + (size_t)blockIdx.z * sA;
    const u16* B = B_ + (size_t)blockIdx.z * sB;

    __shared__ __align__(16) u16 As[2][256 * 64];
    __shared__ __align__(16) u16 Bs[2][BN * 64];

    // staging: thread t loads 16B; row r0 = t>>3, slot t&7 holds chunk c0/8
    const int r0 = tid >> 3;                       // 0..63
    const int c0 = ((tid & 7) ^ (r0 & 7)) * 8;     // pre-swizzled source col
    u32 aoffs[4], boffs[NB];
#pragma unroll
    for (int j = 0; j < 4; j++)
        aoffs[j] = (u32)((m0 + j * 64 + r0) * lda + c0);
#pragma unroll
    for (int j = 0; j < NB; j++)
        boffs[j] = (u32)((n0 + j * 64 + r0) * ldb + c0);
    const int stageDst = wid << 9;                 // wave-uniform LDS elems

    const int nt = K >> 6;                         // K-tiles (8 or 32, even)

    f32x4 acc[8][NJ];
#pragma unroll
    for (int mi = 0; mi < 8; mi++)
#pragma unroll
        for (int nj = 0; nj < NJ; nj++)
#pragma unroll
            for (int r = 0; r < 4; r++) acc[mi][nj][r] = 0.f;

    auto stage = [&](u16* dA, u16* dB, int k0) {
#pragma unroll
        for (int j = 0; j < 4; j++)
            gl16(A + aoffs[j] + k0, dA + (j << 12) + stageDst);
#pragma unroll
        for (int j = 0; j < NB; j++)
            gl16(B + boffs[j] + k0, dB + (j << 12) + stageDst);
    };
    // frag reads: lane l -> row base + (l&15), k-chunk = ks*4 + (l>>4)
    auto rdA = [&](const u16* buf, int p, int h, int ks) -> f16x8 {
        const int row = (wm << 7) + (p << 5) + (h << 4) + l15;
        const int off = (row << 6) + ((((ks << 2) + lq) ^ (row & 7)) << 3);
        return *(const f16x8*)(buf + off);
    };
    auto rdB = [&](const u16* buf, int nj, int ks) -> f16x8 {
        const int row = colB + (nj << 4) + l15;
        const int off = (row << 6) + ((((ks << 2) + lq) ^ (row & 7)) << 3);
        return *(const f16x8*)(buf + off);
    };

    // tile body: 4 phases; P3 = boundary (stage t+2 after lgkm0+barrier,
    // counted vmcnt after MFMA, then barrier into next tile).
    auto tile = [&](u16* Ab, u16* Bb, int tt) {
        f16x8 bfr[NJ][2];
#pragma unroll
        for (int p = 0; p < 4; p++) {
            f16x8 a[2][2];
            if (p == 0) {
#pragma unroll
                for (int nj = 0; nj < NJ; nj++)
#pragma unroll
                    for (int ks = 0; ks < 2; ks++)
                        bfr[nj][ks] = rdB(Bb, nj, ks);
            }
#pragma unroll
            for (int h = 0; h < 2; h++)
#pragma unroll
                for (int ks = 0; ks < 2; ks++)
                    a[h][ks] = rdA(Ab, p, h, ks);
            if (p == 3) {
                // all our LDS reads of this buffer must be IN REGISTERS
                // before any wave overwrites it after the barrier.
                asm volatile("s_waitcnt lgkmcnt(0)" ::: "memory");
                __builtin_amdgcn_sched_barrier(0);
            }
            __builtin_amdgcn_s_barrier();
            if (p == 3 && tt + 2 < nt)
                stage(Ab, Bb, (tt + 2) * 64);      // overwrite now safe
            __builtin_amdgcn_s_setprio(1);
#pragma unroll
            for (int h = 0; h < 2; h++)
#pragma unroll
                for (int nj = 0; nj < NJ; nj++)
#pragma unroll
                    for (int ks = 0; ks < 2; ks++)
                        acc[2 * p + h][nj] =
                            mfma16(a[h][ks], bfr[nj][ks], acc[2 * p + h][nj]);
            __builtin_amdgcn_s_setprio(0);
            if (p < 3) {
                __builtin_amdgcn_s_barrier();
            } else if (tt + 1 < nt) {
                // counted wait: tile tt+1's loads (issued one boundary ago)
                // landed; only tile tt+2's burst stays in flight.
                if (tt + 2 < nt) {
                    if constexpr (BN == 256)
                        asm volatile("s_waitcnt vmcnt(8)" ::: "memory");
                    else
                        asm volatile("s_waitcnt vmcnt(6)" ::: "memory");
                } else {
                    asm volatile("s_waitcnt vmcnt(0)" ::: "memory");
                }
                __builtin_amdgcn_sched_barrier(0);
                __builtin_amdgcn_s_barrier();
            }
        }
    };

    // prologue: stage tiles 0 and 1, counted wait for tile 0.
    stage(As[0], Bs[0], 0);
    stage(As[1], Bs[1], 64);
    if constexpr (BN == 256)
        asm volatile("s_waitcnt vmcnt(8)" ::: "memory");
    else
        asm volatile("s_waitcnt vmcnt(6)" ::: "memory");
    __builtin_amdgcn_sched_barrier(0);
    __builtin_amdgcn_s_barrier();

    for (int tt = 0; tt < nt; tt += 2) {
        tile(As[0], Bs[0], tt);
        tile(As[1], Bs[1], tt + 1);
    }

    // ---- epilogue: 16x16 C/D layout col=lane&15, row=(lane>>4)*4+reg ----
    if (EPI == 2) {
        const int mode = n0 >> 9;   // 0=q 1=k 2=v (BN=256 never straddles)
#pragma unroll
        for (int nj = 0; nj < NJ; nj++) {
            const int gcol = n0 + colB + nj * 16 + l15;
            const int lcol = gcol & 511;
            const float badd = biasf[gcol];
#pragma unroll
            for (int mi = 0; mi < 8; mi++)
#pragma unroll
                for (int r = 0; r < 4; r++) {
                    const int row = m0 + (wm << 7) + mi * 16 + lq * 4 + r;
                    const float v = acc[mi][nj][r] + badd;
                    if (mode == 0)      Oq [(size_t)row * 512 + lcol] = f2h(v);
                    else if (mode == 1) Ok [(size_t)row * 512 + lcol] = f2h(v);
                    else                OvT[(size_t)lcol * 16384 + row] = f2h(v);
                }
        }
    } else if (EPI == 0) {
        float* Cf = (float*)Cp;
        const long coff = (long)blockIdx.z * sC;
#pragma unroll
        for (int nj = 0; nj < NJ; nj++) {
            const int col = n0 + colB + nj * 16 + l15;
#pragma unroll
            for (int mi = 0; mi < 8; mi++)
#pragma unroll
                for (int r = 0; r < 4; r++) {
                    const int row = m0 + (wm << 7) + mi * 16 + lq * 4 + r;
                    Cf[(size_t)(coff + (long)row * ldc + col)] = acc[mi][nj][r];
                }
        }
    } else {
        const int isbf = *flagp;
        float* Cf = (float*)Cp;
        u16* Cb = (u16*)Cp;
        const long coff = cbase + (long)blockIdx.z * sC;
#pragma unroll
        for (int nj = 0; nj < NJ; nj++) {
            const int col = n0 + colB + nj * 16 + l15;
#pragma unroll
            for (int mi = 0; mi < 8; mi++)
#pragma unroll
                for (int r = 0; r < 4; r++) {
                    const int row = m0 + (wm << 7) + mi * 16 + lq * 4 + r;
                    const size_t idx = (size_t)(coff + (long)row * ldc + col);
                    if (isbf) Cb[idx] = f2bf(acc[mi][nj][r]);
                    else Cf[idx] = acc[mi][nj][r];
                }
        }
    }
}

// ---- softmax: fp32 row -> fp16 P in place (first half of row bytes) ----
__global__ __launch_bounds__(256) void softmax_k(float* __restrict__ sc)
{
    float* srow = sc + (size_t)blockIdx.x * S_LEN;
    const int tid = threadIdx.x;

    float4 a = ((const float4*)srow)[tid];
    float4 b = ((const float4*)srow)[256 + tid];

    float m = fmaxf(fmaxf(fmaxf(a.x, a.y), fmaxf(a.z, a.w)),
                    fmaxf(fmaxf(b.x, b.y), fmaxf(b.z, b.w)));
#pragma unroll
    for (int off = 32; off > 0; off >>= 1) m = fmaxf(m, __shfl_down(m, off));

    __shared__ float redm[4], reds[4];
    if ((tid & 63) == 0) redm[tid >> 6] = m;
    __syncthreads();
    m = fmaxf(fmaxf(redm[0], redm[1]), fmaxf(redm[2], redm[3]));

    a.x = __expf(a.x - m); a.y = __expf(a.y - m);
    a.z = __expf(a.z - m); a.w = __expf(a.w - m);
    b.x = __expf(b.x - m); b.y = __expf(b.y - m);
    b.z = __expf(b.z - m); b.w = __expf(b.w - m);
    float s = a.x + a.y + a.z + a.w + b.x + b.y + b.z + b.w;
#pragma unroll
    for (int off = 32; off > 0; off >>= 1) s += __shfl_down(s, off);
    if ((tid & 63) == 0) reds[tid >> 6] = s;
    __syncthreads();
    s = reds[0] + reds[1] + reds[2] + reds[3];

    const float inv = 1.0f / s;
    ushort4 pa, pb;
    pa.x = f2h(a.x * inv); pa.y = f2h(a.y * inv);
    pa.z = f2h(a.z * inv); pa.w = f2h(a.w * inv);
    pb.x = f2h(b.x * inv); pb.y = f2h(b.y * inv);
    pb.z = f2h(b.z * inv); pb.w = f2h(b.w * inv);
    ((ushort4*)srow)[tid] = pa;
    ((ushort4*)srow)[256 + tid] = pb;
}

extern "C" void kernel_launch(void* const* d_in, const int* in_sizes, int n_in,
                              void* d_out, int out_size, void* d_ws, size_t ws_size,
                              hipStream_t stream)
{
    const void* x  = d_in[0];
    const void* Wq = d_in[1]; const void* bq = d_in[2];
    const void* Wk = d_in[3]; const void* bk = d_in[4];
    const void* Wv = d_in[5]; const void* bv = d_in[6];

    const int S = S_LEN, D = D_DIM;
    const long SD = (long)S * D;                      // 1,048,576

    char* w = (char*)d_ws;
    int*   flag = (int*)w;                            // @0
    u16*   WT   = (u16*)(w + 1024);                   // 1,572,864
    float* bcat = (float*)(w + 1573888);              // 6,144
    u16*   xf   = (u16*)(w + 1580032);                // 16,777,216
    u16*   qf   = (u16*)(w + 18357248);
    u16*   kf   = (u16*)(w + 35134464);
    u16*   vT   = (u16*)(w + 51911680);               // [512][16384]
    float* scA  = (float*)(w + 68688896);             // scores arena

    const size_t avail = ws_size > 68688896ull ? ws_size - 68688896ull : 0;
    const size_t perb = (size_t)S * S * 4;
    const int c = avail >= 8 * perb ? 8 : avail >= 4 * perb ? 4 : avail >= 2 * perb ? 2 : 1;

    dim3 blk(256), blk5(512);

    detect_k<<<1, 64, 0, stream>>>((const u16*)x, flag);
    cvt_x<<<8192, blk, 0, stream>>>(x, xf, flag);
    pack_w<<<dim3(512, 6), blk, 0, stream>>>(Wq, Wk, Wv, WT, flag);
    pack_bias<<<6, blk, 0, stream>>>(bq, bk, bv, bcat, flag);

    // fused q|k|v projection: [16384,512] x [512,1536]^T(packed WT)
    gemm8<2, 256><<<dim3(6, 64, 1), blk5, 0, stream>>>(
        xf, WT, nullptr, bcat, qf, kf, vT, flag,
        512, 512, 512, 0, 0, 0, 0, 0);

    for (int cb = 0; cb < B_N; cb += c) {
        const size_t off = (size_t)cb * SD;
        // scores = q k^T (fp32)
        gemm8<0, 256><<<dim3(8, 8, c), blk5, 0, stream>>>(
            qf + off, kf + off, scA, nullptr, nullptr, nullptr, nullptr, flag,
            512, 512, 512, S, SD, SD, (long)S * S, 0);
        softmax_k<<<c * S, blk, 0, stream>>>(scA);
        // out = P @ v via vT rows; P fp16 over fp32 rows (lda = 2S)
        gemm8<1, 128><<<dim3(4, 8, c), blk5, 0, stream>>>(
            (const u16*)scA, vT + (size_t)cb * S, d_out, nullptr,
            nullptr, nullptr, nullptr, flag,
            S, 2 * S, B_N * S, D, 2ll * S * S, S, SD, (long)cb * SD);
    }
}